// Round 12
// baseline (1326.455 us; speedup 1.0000x reference)
//
#include <hip/hip_runtime.h>
#include <hip/hip_bf16.h>

// EdgeGNN: 3x EdgeConv(mean) + final linear.
// Algebra: h'_i = relu( [h_i | mean_j h_j] @ [Wtop - Wbot; Wbot] + b ), 0 if deg==0.
// R18: mega-kernel, barriers made WARM + BALANCED.
// R17 post-mortem: 9 barriers x 8 buffer_inv = every phase starts with cold L2s
// (FETCH 389MB @ 1.36TB/s avg) + static grid-stride pays max-block straggler time.
// Fixes: (1) inv dropped on the 6 layer barriers — all cross-phase dataflow there is
// write-once -> wbL2 -> first-touch read (Hbar triple-buffered; Ucat col-blocks are
// 512B-aligned so lines never straddle; re-read lines are clean copies of unchanged
// data — safe at L1+L2). Control barriers (P0/scan/fill) keep wb+inv. (2) work-stealing:
// per-wave tickets for agg, per-block tickets for GEMM tiles. Bodies unchanged (R10).

typedef short short8 __attribute__((ext_vector_type(8)));
typedef unsigned short ushort8v __attribute__((ext_vector_type(8)));
typedef float float4v __attribute__((ext_vector_type(4)));

static __device__ __forceinline__ float bf2f(unsigned short u) {
    union { unsigned int i; float f; } c; c.i = ((unsigned int)u) << 16; return c.f;
}
static __device__ __forceinline__ unsigned short f2bf(float f) {
    union { float f; unsigned int i; } c; c.f = f;
    unsigned int u = c.i;
    return (unsigned short)((u + 0x7FFFu + ((u >> 16) & 1u)) >> 16);  // RNE
}

#define LDK 72
#define SMEM_BYTES 18432
#define BARR_STRIDE 256

static __device__ __forceinline__ int get_xcd() {
    int v;
    asm volatile("s_getreg_b32 %0, hwreg(HW_REG_XCC_ID)" : "=s"(v));
    return v & 7;
}

// Grid barrier, single-use counters (zeroed by host memset). Per-XCD leader does wbL2
// after all arrivals; waits all XCDs flushed; optional invL2; raises per-XCD V flag.
// Non-leaders poll V with relaxed RMW (no cache ops).
static __device__ __forceinline__ void gbar(int* barr, int p, int nb, int xcd, int* nxcd,
                                            bool doInv) {
    __syncthreads();  // block's stores drained to L2
    if (threadIdx.x == 0) {
        int* base = barr + 256 + p * BARR_STRIDE;
        __hip_atomic_fetch_add(base + 0, 1, __ATOMIC_RELAXED, __HIP_MEMORY_SCOPE_AGENT);
        int lead = __hip_atomic_fetch_add(base + 32 + xcd, 1, __ATOMIC_RELAXED,
                                          __HIP_MEMORY_SCOPE_AGENT);
        if (lead == 0) {
            while (__hip_atomic_fetch_add(base + 0, 0, __ATOMIC_RELAXED,
                                          __HIP_MEMORY_SCOPE_AGENT) < nb)
                __builtin_amdgcn_s_sleep(4);
            __builtin_amdgcn_fence(__ATOMIC_RELEASE, "agent");   // buffer_wbl2: publish
            asm volatile("s_waitcnt vmcnt(0)" ::: "memory");
            __hip_atomic_fetch_add(base + 16, 1, __ATOMIC_RELAXED, __HIP_MEMORY_SCOPE_AGENT);
            int nx = __hip_atomic_fetch_add(nxcd, 0, __ATOMIC_RELAXED,
                                            __HIP_MEMORY_SCOPE_AGENT);
            while (__hip_atomic_fetch_add(base + 16, 0, __ATOMIC_RELAXED,
                                          __HIP_MEMORY_SCOPE_AGENT) < nx)
                __builtin_amdgcn_s_sleep(4);
            if (doInv) {
                __builtin_amdgcn_fence(__ATOMIC_ACQUIRE, "agent");  // buffer_inv
                asm volatile("s_waitcnt vmcnt(0)" ::: "memory");
            }
            __hip_atomic_fetch_add(base + 64 + xcd * 16, 1, __ATOMIC_RELAXED,
                                   __HIP_MEMORY_SCOPE_AGENT);
        } else {
            while (__hip_atomic_fetch_add(base + 64 + xcd * 16, 0, __ATOMIC_RELAXED,
                                          __HIP_MEMORY_SCOPE_AGENT) < 1)
                __builtin_amdgcn_s_sleep(16);
        }
    }
    __syncthreads();
    asm volatile("" ::: "memory");
}

static __device__ __forceinline__ int wave_steal(int* q, int lane) {
    int v = 0;
    if (lane == 0)
        v = __hip_atomic_fetch_add(q, 1, __ATOMIC_RELAXED, __HIP_MEMORY_SCOPE_AGENT);
    return __shfl(v, 0);
}

// ---------------- GEMM tile body (64x64), verbatim from R10 gemm_kernel ----------------
template <int MODE, int K>
static __device__ void gemm_body(int bm, int bn,
                                 const unsigned short* __restrict__ A1,
                                 const unsigned short* __restrict__ A2,
                                 const unsigned short* __restrict__ Bt,
                                 const float* __restrict__ bias,
                                 const int* __restrict__ deg,
                                 unsigned short* __restrict__ outB,
                                 float* __restrict__ outF,
                                 int M, unsigned char* smem) {
    unsigned short* ldsA = (unsigned short*)smem;
    unsigned short* ldsB = ldsA + 64 * LDK;
    constexpr int NIT = K / 64;
    int t = threadIdx.x;
    int lane = t & 63, wave = t >> 6;
    int wm = wave >> 1, wn = wave & 1;
    int lr = lane & 15, q = lane >> 4;

    float4v acc[2][2];
#pragma unroll
    for (int i = 0; i < 2; i++)
#pragma unroll
        for (int j = 0; j < 2; j++) { float4v z = {0.f, 0.f, 0.f, 0.f}; acc[i][j] = z; }

    int r = t >> 2;
    int quarter = t & 3;
    int rowA = bm * 64 + r;
    if (rowA >= M) rowA = M - 1;  // clamp: duplicate row, stores masked below
    const unsigned short* gB0 = Bt + (long)(bn * 64 + r) * K + quarter * 16;
    unsigned short* sA = ldsA + r * LDK + quarter * 16;
    unsigned short* sB = ldsB + r * LDK + quarter * 16;

    auto addrA = [&](int kk) -> const unsigned short* {
        if (MODE == 1 || kk < 256) return A1 + (long)rowA * 1024 + kk + quarter * 16;
        return A2 + (long)rowA * 256 + (kk - 256) + quarter * 16;
    };

    const unsigned short* pa = addrA(0);
    uint4 a0 = *(const uint4*)pa;
    uint4 a1 = *(const uint4*)(pa + 8);
    uint4 b0 = *(const uint4*)gB0;
    uint4 b1 = *(const uint4*)(gB0 + 8);

    for (int it = 0; it < NIT; ++it) {
        __syncthreads();
        *(uint4*)sA = a0; *(uint4*)(sA + 8) = a1;
        *(uint4*)sB = b0; *(uint4*)(sB + 8) = b1;
        __syncthreads();
        if (it + 1 < NIT) {
            int kn = (it + 1) << 6;
            const unsigned short* pn = addrA(kn);
            a0 = *(const uint4*)pn;
            a1 = *(const uint4*)(pn + 8);
            b0 = *(const uint4*)(gB0 + kn);
            b1 = *(const uint4*)(gB0 + kn + 8);
        }
#pragma unroll
        for (int ks = 0; ks < 2; ++ks) {
            short8 af[2], bfr[2];
#pragma unroll
            for (int mi = 0; mi < 2; ++mi)
                af[mi] = *(const short8*)(ldsA + (wm * 32 + mi * 16 + lr) * LDK + ks * 32 + q * 8);
#pragma unroll
            for (int ni = 0; ni < 2; ++ni)
                bfr[ni] = *(const short8*)(ldsB + (wn * 32 + ni * 16 + lr) * LDK + ks * 32 + q * 8);
#pragma unroll
            for (int mi = 0; mi < 2; ++mi)
#pragma unroll
                for (int ni = 0; ni < 2; ++ni)
                    acc[mi][ni] = __builtin_amdgcn_mfma_f32_16x16x32_bf16(af[mi], bfr[ni], acc[mi][ni], 0, 0, 0);
        }
    }

    __syncthreads();  // all waves done reading ldsA/ldsB; reuse smem for C tile

    if (MODE == 0) {
        unsigned short* C = (unsigned short*)smem;
#pragma unroll
        for (int mi = 0; mi < 2; ++mi) {
#pragma unroll
            for (int ni = 0; ni < 2; ++ni) {
                int cn = wn * 32 + ni * 16 + lr;
                float bv = bias[bn * 64 + cn];
                int rl0 = wm * 32 + mi * 16 + q * 4;
#pragma unroll
                for (int r4 = 0; r4 < 4; ++r4) {
                    float v = fmaxf(acc[mi][ni][r4] + bv, 0.0f);
                    C[(rl0 + r4) * LDK + cn] = f2bf(v);
                }
            }
        }
        __syncthreads();
#pragma unroll
        for (int j = 0; j < 2; ++j) {
            int chunk = t + j * 256;
            int row = chunk >> 3, h = chunk & 7;
            int rg = bm * 64 + row;
            if (rg < M) {
                short8 v = *(const short8*)(C + row * LDK + h * 8);
                if (deg[rg] <= 0) { short8 z = {0, 0, 0, 0, 0, 0, 0, 0}; v = z; }
                *(short8*)(outB + (long)rg * 1024 + bn * 64 + h * 8) = v;
            }
        }
    } else {
        float* Cf = (float*)smem;
#pragma unroll
        for (int mi = 0; mi < 2; ++mi) {
#pragma unroll
            for (int ni = 0; ni < 2; ++ni) {
                int cn = wn * 32 + ni * 16 + lr;
                float bv = bias[bn * 64 + cn];
                int rl0 = wm * 32 + mi * 16 + q * 4;
#pragma unroll
                for (int r4 = 0; r4 < 4; ++r4)
                    Cf[(rl0 + r4) * 68 + cn] = acc[mi][ni][r4] + bv;
            }
        }
        __syncthreads();
#pragma unroll
        for (int j = 0; j < 4; ++j) {
            int chunk = t + j * 256;
            int row = chunk >> 4, h = chunk & 15;
            int rg = bm * 64 + row;
            if (rg < M) {
                float4 v = *(const float4*)(Cf + row * 68 + h * 4);
                *(float4*)(outF + (long)rg * 256 + bn * 64 + h * 4) = v;
            }
        }
    }
    __syncthreads();  // epilogue LDS reads done before next tile's writes
}

// ---------------- agg node body: R7 two-row gather, one node per wave ----------------
static __device__ void agg_node(int i, const unsigned short* __restrict__ H,
                                const int* __restrict__ offs, const int* __restrict__ esrc,
                                unsigned short* __restrict__ Hbar, int N) {
    int lane = threadIdx.x & 63;
    int half = lane >> 5;
    int c = (lane & 31) * 8;
    float a[8];
#pragma unroll
    for (int j = 0; j < 8; ++j) a[j] = 0.f;
    int e0 = offs[i], e1 = offs[i + 1];
    int e = e0;
    for (; e + 8 <= e1; e += 8) {
        int p0 = esrc[e],     p1 = esrc[e + 1];
        int p2 = esrc[e + 2], p3 = esrc[e + 3];
        int p4 = esrc[e + 4], p5 = esrc[e + 5];
        int p6 = esrc[e + 6], p7 = esrc[e + 7];
        int s0 = half ? p1 : p0;
        int s1 = half ? p3 : p2;
        int s2 = half ? p5 : p4;
        int s3 = half ? p7 : p6;
        ushort8v r0 = *(const ushort8v*)(H + (long)s0 * 1024 + c);
        ushort8v r1 = *(const ushort8v*)(H + (long)s1 * 1024 + c);
        ushort8v r2 = *(const ushort8v*)(H + (long)s2 * 1024 + c);
        ushort8v r3 = *(const ushort8v*)(H + (long)s3 * 1024 + c);
#pragma unroll
        for (int j = 0; j < 8; ++j)
            a[j] += (bf2f(r0[j]) + bf2f(r1[j])) + (bf2f(r2[j]) + bf2f(r3[j]));
    }
    for (; e + 4 <= e1; e += 4) {
        int p0 = esrc[e],     p1 = esrc[e + 1];
        int p2 = esrc[e + 2], p3 = esrc[e + 3];
        int s0 = half ? p1 : p0;
        int s1 = half ? p3 : p2;
        ushort8v r0 = *(const ushort8v*)(H + (long)s0 * 1024 + c);
        ushort8v r1 = *(const ushort8v*)(H + (long)s1 * 1024 + c);
#pragma unroll
        for (int j = 0; j < 8; ++j)
            a[j] += bf2f(r0[j]) + bf2f(r1[j]);
    }
    for (; e < e1; e += 2) {
        int pa = esrc[e];
        int pb = (e + 1 < e1) ? esrc[e + 1] : pa;
        int s = half ? pb : pa;
        float m = (half && (e + 1 >= e1)) ? 0.f : 1.f;
        ushort8v r = *(const ushort8v*)(H + (long)s * 1024 + c);
#pragma unroll
        for (int j = 0; j < 8; ++j)
            a[j] = fmaf(bf2f(r[j]), m, a[j]);
    }
    int d = e1 - e0;
    float inv = (d > 0) ? 1.0f / (float)d : 0.0f;
    ushort8v w;
#pragma unroll
    for (int j = 0; j < 8; ++j) {
        float tsum = a[j] + __shfl_xor(a[j], 32);
        w[j] = f2bf(tsum * inv);
    }
    if (half == 0)
        *(ushort8v*)(Hbar + (long)i * 256 + c) = w;
}

// ---------------- mega kernel ----------------
__global__ __launch_bounds__(256, 6)
void mega_kernel(const float* __restrict__ x,
                 const int* __restrict__ src, const int* __restrict__ dst, int E,
                 const float* __restrict__ W0, const float* __restrict__ W1,
                 const float* __restrict__ W2, const float* __restrict__ Wf,
                 const float* __restrict__ b0p, const float* __restrict__ b1p,
                 const float* __restrict__ b2p, const float* __restrict__ bfp,
                 int* __restrict__ deg, int* __restrict__ offs, int* __restrict__ cursor,
                 int* __restrict__ esrc,
                 unsigned short* __restrict__ Wc0, unsigned short* __restrict__ Wc1,
                 unsigned short* __restrict__ Wc2, unsigned short* __restrict__ Wft,
                 unsigned short* __restrict__ Ucat, unsigned short* __restrict__ Hbar,
                 float* __restrict__ out, int* __restrict__ barr,
                 int N, int EB, int xblocks, int nbScan) {
    __shared__ __align__(16) unsigned char smem[SMEM_BYTES];
    __shared__ int vbs;
    int bid = blockIdx.x, t = threadIdx.x;
    int lane = t & 63;
    int NB = gridDim.x;
    int xcd = get_xcd();
    int* nxcd = barr + 128;

    // start election: count distinct XCDs hosting blocks
    if (t == 0) {
        int first = __hip_atomic_fetch_add(barr + xcd * 16, 1, __ATOMIC_RELAXED,
                                           __HIP_MEMORY_SCOPE_AGENT);
        if (first == 0)
            __hip_atomic_fetch_add(nxcd, 1, __ATOMIC_RELAXED, __HIP_MEMORY_SCOPE_AGENT);
    }

    // ================= P0: deg count + W-prep + x->bf16 =================
    {
        float(*ta)[33] = (float(*)[33])smem;
        float(*tb)[33] = (float(*)[33])(smem + 32 * 33 * 4);
        int vbTot = EB + 448 + xblocks;
        for (int bb = bid; bb < vbTot; bb += NB) {
            if (bb < EB) {
                int idx = bb * 256 + t;
                if (idx < E) atomicAdd(&deg[dst[idx]], 1);
            } else {
                int bb2 = bb - EB;
                int r0 = t >> 5, c = t & 31;
                if (bb2 < 192) {
                    const float* W = (bb2 < 64) ? W0 : (bb2 < 128) ? W1 : W2;
                    unsigned short* Wc = (bb2 < 64) ? Wc0 : (bb2 < 128) ? Wc1 : Wc2;
                    int t64 = bb2 & 63;
                    int k0 = (t64 >> 3) * 32, n0 = (t64 & 7) * 32;
#pragma unroll
                    for (int it = 0; it < 4; ++it) {
                        int r = r0 + it * 8;
                        float a = W[(k0 + r) * 256 + n0 + c];
                        float bv = W[(k0 + r + 256) * 256 + n0 + c];
                        ta[r][c] = a - bv;
                        tb[r][c] = bv;
                    }
                    __syncthreads();
#pragma unroll
                    for (int it = 0; it < 4; ++it) {
                        int r = r0 + it * 8;
                        Wc[(n0 + r) * 512 + k0 + c] = f2bf(ta[c][r]);
                        Wc[(n0 + r) * 512 + 256 + k0 + c] = f2bf(tb[c][r]);
                    }
                    __syncthreads();  // LDS reuse across grid-stride iters
                } else if (bb2 < 448) {
                    int t256 = bb2 - 192;
                    int k0 = (t256 >> 3) * 32, n0 = (t256 & 7) * 32;
#pragma unroll
                    for (int it = 0; it < 4; ++it) {
                        int r = r0 + it * 8;
                        ta[r][c] = Wf[(k0 + r) * 256 + n0 + c];
                    }
                    __syncthreads();
#pragma unroll
                    for (int it = 0; it < 4; ++it) {
                        int r = r0 + it * 8;
                        Wft[(n0 + r) * 1024 + k0 + c] = f2bf(ta[c][r]);
                    }
                    __syncthreads();  // LDS reuse across grid-stride iters
                } else {
                    long base = (long)(bb2 - 448) * 2048 + t * 8;
                    if (base < (long)N * 256) {
                        int i = (int)(base >> 8), cc = (int)(base & 255);
                        const float4* xp = (const float4*)(x + base);
                        float4 v0 = xp[0], v1 = xp[1];
                        ushort4 w0, w1;
                        w0.x = f2bf(v0.x); w0.y = f2bf(v0.y); w0.z = f2bf(v0.z); w0.w = f2bf(v0.w);
                        w1.x = f2bf(v1.x); w1.y = f2bf(v1.y); w1.z = f2bf(v1.z); w1.w = f2bf(v1.w);
                        unsigned short* up = Ucat + (long)i * 1024 + cc;
                        *(ushort4*)up = w0;
                        *(ushort4*)(up + 4) = w1;
                    }
                }
            }
        }
    }
    gbar(barr, 0, NB, xcd, nxcd, true);

    // ================= P1: CSR scan (redundant-prefix), blocks [0,nbScan) =================
    if (bid < nbScan) {
        int* part = (int*)smem;          // [256]
        int* pre = (int*)smem + 256;     // [128]
        int b = bid;
        int beg = b * 128;
        int end = beg + 128; if (end > N) end = N;
        int s = 0;
        for (int i = t; i < beg; i += 256) s += deg[i];
        part[t] = s;
        __syncthreads();
#pragma unroll
        for (int off = 128; off > 0; off >>= 1) {
            if (t < off) part[t] += part[t + off];
            __syncthreads();
        }
        int base = part[0];
        int cnt = end - beg;
        if (t < 128) pre[t] = (t < cnt) ? deg[beg + t] : 0;
        __syncthreads();
        for (int off = 1; off < 128; off <<= 1) {
            int v = 0;
            if (t < 128 && t >= off) v = pre[t - off];
            __syncthreads();
            if (t < 128 && t >= off) pre[t] += v;
            __syncthreads();
        }
        if (t < cnt) {
            int excl = base + (t ? pre[t - 1] : 0);
            offs[beg + t] = excl;
            cursor[beg + t] = excl;
        }
        if (end == N && t == 0) offs[N] = base + (cnt ? pre[cnt - 1] : 0);
    }
    gbar(barr, 1, NB, xcd, nxcd, true);

    // ================= P2: bucket fill =================
    for (int idx = bid * 256 + t; idx < E; idx += NB * 256) {
        int p = atomicAdd(&cursor[dst[idx]], 1);
        esrc[p] = src[idx];
    }
    gbar(barr, 2, NB, xcd, nxcd, true);

    // ================= layers (wb-only barriers; work-stealing) =================
    int gm = (N + 63) / 64;
    int tiles = gm * 4;
#pragma unroll 1
    for (int l = 0; l < 3; ++l) {
        const unsigned short* A1 = Ucat + l * 256;
        const unsigned short* Wc = (l == 0) ? Wc0 : (l == 1) ? Wc1 : Wc2;
        const float* bias = (l == 0) ? b0p : (l == 1) ? b1p : b2p;
        unsigned short* outB = Ucat + (l + 1) * 256;
        unsigned short* Hb = Hbar + (long)l * ((long)N * 256);  // triple buffer: no rewrite
        int* aggQ = barr + 144 + l;
        int* gemQ = barr + 152 + l;

        for (;;) {   // per-wave steal: one node per ticket
            int i = wave_steal(aggQ, lane);
            if (i >= N) break;
            agg_node(i, A1, offs, esrc, Hb, N);
        }
        gbar(barr, 3 + 2 * l, NB, xcd, nxcd, false);

        for (;;) {   // per-block steal: one 64x64 tile per ticket
            if (t == 0)
                vbs = __hip_atomic_fetch_add(gemQ, 1, __ATOMIC_RELAXED,
                                             __HIP_MEMORY_SCOPE_AGENT);
            __syncthreads();
            int vb = vbs;
            if (vb >= tiles) break;
            gemm_body<0, 512>(vb % gm, vb / gm, A1, Hb, Wc, bias, deg, outB, nullptr, N, smem);
        }
        gbar(barr, 4 + 2 * l, NB, xcd, nxcd, false);
    }

    // ================= final linear =================
    {
        int* finQ = barr + 160;
        for (;;) {
            if (t == 0)
                vbs = __hip_atomic_fetch_add(finQ, 1, __ATOMIC_RELAXED,
                                             __HIP_MEMORY_SCOPE_AGENT);
            __syncthreads();
            int vb = vbs;
            if (vb >= tiles) break;
            gemm_body<1, 1024>(vb % gm, vb / gm, Ucat, nullptr, Wft, bfp, nullptr, nullptr,
                               out, N, smem);
        }
    }
}

extern "C" void kernel_launch(void* const* d_in, const int* in_sizes, int n_in,
                              void* d_out, int out_size, void* d_ws, size_t ws_size,
                              hipStream_t stream) {
    const float* x = (const float*)d_in[0];
    const int* ei = (const int*)d_in[1];
    const float* W[3] = {(const float*)d_in[2], (const float*)d_in[4], (const float*)d_in[6]};
    const float* b[3] = {(const float*)d_in[3], (const float*)d_in[5], (const float*)d_in[7]};
    const float* Wfp = (const float*)d_in[8];
    const float* bfp = (const float*)d_in[9];

    int N = in_sizes[0] / 256;
    int E = in_sizes[1] / 2;
    const int* src = ei;
    const int* dst = ei + E;

    char* p = (char*)d_ws;
    auto alloc = [&](size_t bytes) { char* r = p; p += (bytes + 255) & ~(size_t)255; return r; };
    size_t degPad = ((size_t)N * 4 + 255) & ~(size_t)255;
    int* deg = (int*)alloc(degPad);
    int* barr = (int*)alloc(16384);               // contiguous after deg (both zeroed below)
    int* offs = (int*)alloc((size_t)(N + 1) * 4);
    int* cursor = (int*)alloc((size_t)N * 4);
    int* esrc = (int*)alloc((size_t)E * 4);
    unsigned short* Wc[3];
    for (int l = 0; l < 3; l++) Wc[l] = (unsigned short*)alloc(256 * 512 * 2);
    unsigned short* Wft = (unsigned short*)alloc(256 * 1024 * 2);
    unsigned short* Ucat = (unsigned short*)alloc((size_t)N * 1024 * 2);
    unsigned short* Hbar = (unsigned short*)alloc((size_t)3 * N * 256 * 2);  // triple

    hipMemsetAsync(deg, 0, degPad + 16384, stream);  // zero deg + barrier region

    int EB = (E + 255) / 256;
    int xblocks = (N * 256 + 2047) / 2048;
    int nbScan = (N + 127) / 128;
    int NB = 1536;  // 6 blocks/CU co-resident under launch_bounds(256,6)+18KB LDS

    mega_kernel<<<NB, 256, 0, stream>>>(x, src, dst, E,
                                        W[0], W[1], W[2], Wfp,
                                        b[0], b[1], b[2], bfp,
                                        deg, offs, cursor, esrc,
                                        Wc[0], Wc[1], Wc[2], Wft,
                                        Ucat, Hbar, (float*)d_out, barr,
                                        N, EB, xblocks, nbScan);
}

// Round 13
// 270.430 us; speedup vs baseline: 4.9050x; 4.9050x over previous
//
#include <hip/hip_runtime.h>
#include <hip/hip_bf16.h>

// EdgeGNN: 3x EdgeConv(mean) + final linear.
// Algebra: h'_i = relu( [h_i | mean_j h_j] @ [Wtop - Wbot; Wbot] + b ), 0 if deg==0.
// R19: REVERT to R10 (best measured, 271.2us), honoring R18's pre-commit. Mega-kernel
// path abandoned after 4 attempts (2713/1875/393/1264us): a correct cross-XCD grid
// barrier costs ~25us (per-XCD L2 wb/inv + stragglers) > the ~12us launch overhead it
// replaces; single-counter work-stealing adds ~1ms of far-atomic serialization (R18).
// Config: fused setup, parallel redundant-prefix scan, fill, R7 two-row-gather agg,
// 64x64 reg-staged MFMA GEMMs with coalesced epilogues.

typedef short short8 __attribute__((ext_vector_type(8)));
typedef unsigned short ushort8v __attribute__((ext_vector_type(8)));
typedef float float4v __attribute__((ext_vector_type(4)));

static __device__ __forceinline__ float bf2f(unsigned short u) {
    union { unsigned int i; float f; } c; c.i = ((unsigned int)u) << 16; return c.f;
}
static __device__ __forceinline__ unsigned short f2bf(float f) {
    union { float f; unsigned int i; } c; c.f = f;
    unsigned int u = c.i;
    return (unsigned short)((u + 0x7FFFu + ((u >> 16) & 1u)) >> 16);  // RNE
}

// ---------------- fused setup: deg count + weight prep + x->bf16 ----------------
// blocks [0,EB): count deg.  [EB,EB+192): layer W -> Wc[l] as [n=256][k=512]
//   Wc[n][k] = bf16(W[k][n] - W[k+256][n]) (k<256);  Wc[n][256+k] = bf16(W[k+256][n])
// [EB+192,EB+448): Wf -> Wft [256][1024].  [EB+448,...): x fp32->bf16 into Ucat col 0.
__global__ __launch_bounds__(256)
void setup_kernel(const int* __restrict__ dst, int E, int* __restrict__ deg,
                  const float* __restrict__ W0, const float* __restrict__ W1,
                  const float* __restrict__ W2, const float* __restrict__ Wf,
                  const float* __restrict__ x,
                  unsigned short* __restrict__ Wc0, unsigned short* __restrict__ Wc1,
                  unsigned short* __restrict__ Wc2, unsigned short* __restrict__ Wft,
                  unsigned short* __restrict__ Ucat, int N, int EB) {
    __shared__ float ta[32][33];
    __shared__ float tb[32][33];
    int bb = blockIdx.x;
    int t = threadIdx.x;
    if (bb < EB) {
        int idx = bb * 256 + t;
        if (idx < E) atomicAdd(&deg[dst[idx]], 1);
        return;
    }
    int bb2 = bb - EB;
    int r0 = t >> 5, c = t & 31;
    if (bb2 < 192) {
        const float* W = (bb2 < 64) ? W0 : (bb2 < 128) ? W1 : W2;
        unsigned short* Wc = (bb2 < 64) ? Wc0 : (bb2 < 128) ? Wc1 : Wc2;
        int t64 = bb2 & 63;
        int k0 = (t64 >> 3) * 32, n0 = (t64 & 7) * 32;
#pragma unroll
        for (int it = 0; it < 4; ++it) {
            int r = r0 + it * 8;
            float a = W[(k0 + r) * 256 + n0 + c];
            float bv = W[(k0 + r + 256) * 256 + n0 + c];
            ta[r][c] = a - bv;
            tb[r][c] = bv;
        }
        __syncthreads();
#pragma unroll
        for (int it = 0; it < 4; ++it) {
            int r = r0 + it * 8;  // row in n-space
            Wc[(n0 + r) * 512 + k0 + c] = f2bf(ta[c][r]);
            Wc[(n0 + r) * 512 + 256 + k0 + c] = f2bf(tb[c][r]);
        }
    } else if (bb2 < 448) {
        int t256 = bb2 - 192;
        int k0 = (t256 >> 3) * 32, n0 = (t256 & 7) * 32;
#pragma unroll
        for (int it = 0; it < 4; ++it) {
            int r = r0 + it * 8;
            ta[r][c] = Wf[(k0 + r) * 256 + n0 + c];
        }
        __syncthreads();
#pragma unroll
        for (int it = 0; it < 4; ++it) {
            int r = r0 + it * 8;
            Wft[(n0 + r) * 1024 + k0 + c] = f2bf(ta[c][r]);
        }
    } else {
        long base = (long)(bb2 - 448) * 2048 + t * 8;
        if (base < (long)N * 256) {
            int i = (int)(base >> 8), cc = (int)(base & 255);
            const float4* xp = (const float4*)(x + base);
            float4 v0 = xp[0], v1 = xp[1];
            ushort4 w0, w1;
            w0.x = f2bf(v0.x); w0.y = f2bf(v0.y); w0.z = f2bf(v0.z); w0.w = f2bf(v0.w);
            w1.x = f2bf(v1.x); w1.y = f2bf(v1.y); w1.z = f2bf(v1.z); w1.w = f2bf(v1.w);
            unsigned short* up = Ucat + (long)i * 1024 + cc;
            *(ushort4*)up = w0;
            *(ushort4*)(up + 4) = w1;
        }
    }
}

// ---------------- CSR scan (redundant-prefix, 157 parallel blocks) + bucket fill ----------
// Block b owns nodes [b*128, min(N,(b+1)*128)). Phase 1: base = sum deg[0..b*128) —
// deg is 80KB, L2-resident, so the redundant reads are cheap and fully parallel.
// Phase 2: 128-wide Hillis-Steele LDS scan of the local slice; write offs/cursor.
__global__ __launch_bounds__(256)
void scan_kernel(const int* __restrict__ deg, int* __restrict__ offs,
                 int* __restrict__ cursor, int N) {
    __shared__ int part[256];
    __shared__ int pre[128];
    int b = blockIdx.x, t = threadIdx.x;
    int beg = b * 128;
    int end = beg + 128; if (end > N) end = N;
    // phase 1: base = sum deg[0..beg)
    int s = 0;
    for (int i = t; i < beg; i += 256) s += deg[i];
    part[t] = s;
    __syncthreads();
#pragma unroll
    for (int off = 128; off > 0; off >>= 1) {
        if (t < off) part[t] += part[t + off];
        __syncthreads();
    }
    int base = part[0];
    // phase 2: local inclusive scan of deg[beg..end)
    int cnt = end - beg;
    if (t < 128) pre[t] = (t < cnt) ? deg[beg + t] : 0;
    __syncthreads();
    for (int off = 1; off < 128; off <<= 1) {
        int v = 0;
        if (t < 128 && t >= off) v = pre[t - off];
        __syncthreads();
        if (t < 128 && t >= off) pre[t] += v;
        __syncthreads();
    }
    if (t < cnt) {
        int excl = base + (t ? pre[t - 1] : 0);
        offs[beg + t] = excl;
        cursor[beg + t] = excl;
    }
    if (end == N && t == 0) offs[N] = base + (cnt ? pre[cnt - 1] : 0);
}

__global__ void fill_kernel(const int* __restrict__ src, const int* __restrict__ dst, int E,
                            int* __restrict__ cursor, int* __restrict__ esrc) {
    int idx = blockIdx.x * 256 + threadIdx.x;
    if (idx < E) {
        int p = atomicAdd(&cursor[dst[idx]], 1);
        esrc[p] = src[idx];
    }
}

// ---------------- gather-mean: Hbar[i] = mean_j H[j] (bf16), one wave per node ----------------
// Two rows per wave-load. lanes 0-31 handle even edge of each pair (cols (lane&31)*8..+7),
// lanes 32-63 the odd edge. One ushort8 load = 16B/lane = 1KB covering 2 full source rows.
__global__ __launch_bounds__(256)
void agg_kernel(const unsigned short* __restrict__ H, const int* __restrict__ offs,
                const int* __restrict__ esrc, unsigned short* __restrict__ Hbar, int N) {
    int wave = threadIdx.x >> 6, lane = threadIdx.x & 63;
    int i = blockIdx.x * 4 + wave;
    if (i >= N) return;
    int half = lane >> 5;            // 0: even edge of pair, 1: odd edge
    int c = (lane & 31) * 8;         // 8 contiguous cols per lane, 32 lanes cover 256
    float a[8];
#pragma unroll
    for (int j = 0; j < 8; ++j) a[j] = 0.f;
    int e0 = offs[i], e1 = offs[i + 1];
    int e = e0;
    for (; e + 8 <= e1; e += 8) {
        int p0 = esrc[e],     p1 = esrc[e + 1];
        int p2 = esrc[e + 2], p3 = esrc[e + 3];
        int p4 = esrc[e + 4], p5 = esrc[e + 5];
        int p6 = esrc[e + 6], p7 = esrc[e + 7];
        int s0 = half ? p1 : p0;
        int s1 = half ? p3 : p2;
        int s2 = half ? p5 : p4;
        int s3 = half ? p7 : p6;
        ushort8v r0 = *(const ushort8v*)(H + (long)s0 * 1024 + c);
        ushort8v r1 = *(const ushort8v*)(H + (long)s1 * 1024 + c);
        ushort8v r2 = *(const ushort8v*)(H + (long)s2 * 1024 + c);
        ushort8v r3 = *(const ushort8v*)(H + (long)s3 * 1024 + c);
#pragma unroll
        for (int j = 0; j < 8; ++j)
            a[j] += (bf2f(r0[j]) + bf2f(r1[j])) + (bf2f(r2[j]) + bf2f(r3[j]));
    }
    for (; e + 4 <= e1; e += 4) {
        int p0 = esrc[e],     p1 = esrc[e + 1];
        int p2 = esrc[e + 2], p3 = esrc[e + 3];
        int s0 = half ? p1 : p0;
        int s1 = half ? p3 : p2;
        ushort8v r0 = *(const ushort8v*)(H + (long)s0 * 1024 + c);
        ushort8v r1 = *(const ushort8v*)(H + (long)s1 * 1024 + c);
#pragma unroll
        for (int j = 0; j < 8; ++j)
            a[j] += bf2f(r0[j]) + bf2f(r1[j]);
    }
    for (; e < e1; e += 2) {
        int pa = esrc[e];
        int pb = (e + 1 < e1) ? esrc[e + 1] : pa;
        int s = half ? pb : pa;
        float m = (half && (e + 1 >= e1)) ? 0.f : 1.f;
        ushort8v r = *(const ushort8v*)(H + (long)s * 1024 + c);
#pragma unroll
        for (int j = 0; j < 8; ++j)
            a[j] = fmaf(bf2f(r[j]), m, a[j]);
    }
    int d = e1 - e0;
    float inv = (d > 0) ? 1.0f / (float)d : 0.0f;
    ushort8v w;
#pragma unroll
    for (int j = 0; j < 8; ++j) {
        float tsum = a[j] + __shfl_xor(a[j], 32);
        w[j] = f2bf(tsum * inv);
    }
    if (half == 0)
        *(ushort8v*)(Hbar + (long)i * 256 + c) = w;
}

// ---------------- bf16 MFMA GEMM, 64x64 tile, LDS-staged K-loop + coalesced epilogue ----------
// A (MODE 0): k<256 from A1 (stride 1024, Ucat window), k>=256 from A2 (stride 256, Hbar).
// A (MODE 1): A1 stride 1024, K=1024.  Bt: [n=256][K] (Wc/Wft).
// Epilogue: stage C in LDS (reusing staging buffer), store 16B-coalesced.
#define LDK 72

template <int MODE, int K>
__global__ __launch_bounds__(256)
void gemm_kernel(const unsigned short* __restrict__ A1,
                 const unsigned short* __restrict__ A2,
                 const unsigned short* __restrict__ Bt,
                 const float* __restrict__ bias,
                 const int* __restrict__ deg,
                 unsigned short* __restrict__ outB,
                 float* __restrict__ outF,
                 int M) {
    __shared__ __align__(16) unsigned char smem[64 * LDK * 2 * 2];  // 18432 B
    unsigned short* ldsA = (unsigned short*)smem;
    unsigned short* ldsB = ldsA + 64 * LDK;
    constexpr int NIT = K / 64;
    int t = threadIdx.x;
    int bm = blockIdx.x, bn = blockIdx.y;
    int lane = t & 63, wave = t >> 6;
    int wm = wave >> 1, wn = wave & 1;
    int lr = lane & 15, q = lane >> 4;

    float4v acc[2][2];
#pragma unroll
    for (int i = 0; i < 2; i++)
#pragma unroll
        for (int j = 0; j < 2; j++) { float4v z = {0.f, 0.f, 0.f, 0.f}; acc[i][j] = z; }

    int r = t >> 2;        // staging row 0..63
    int quarter = t & 3;   // 16-elem chunk within the 64-elem k-slice
    int rowA = bm * 64 + r;
    if (rowA >= M) rowA = M - 1;  // clamp: duplicate row, stores masked below
    const unsigned short* gB0 = Bt + (long)(bn * 64 + r) * K + quarter * 16;
    unsigned short* sA = ldsA + r * LDK + quarter * 16;
    unsigned short* sB = ldsB + r * LDK + quarter * 16;

    auto addrA = [&](int kk) -> const unsigned short* {
        if (MODE == 1 || kk < 256) return A1 + (long)rowA * 1024 + kk + quarter * 16;
        return A2 + (long)rowA * 256 + (kk - 256) + quarter * 16;
    };

    // prologue
    const unsigned short* pa = addrA(0);
    uint4 a0 = *(const uint4*)pa;
    uint4 a1 = *(const uint4*)(pa + 8);
    uint4 b0 = *(const uint4*)gB0;
    uint4 b1 = *(const uint4*)(gB0 + 8);

    for (int it = 0; it < NIT; ++it) {
        __syncthreads();
        *(uint4*)sA = a0; *(uint4*)(sA + 8) = a1;
        *(uint4*)sB = b0; *(uint4*)(sB + 8) = b1;
        __syncthreads();
        if (it + 1 < NIT) {
            int kn = (it + 1) << 6;
            const unsigned short* pn = addrA(kn);
            a0 = *(const uint4*)pn;
            a1 = *(const uint4*)(pn + 8);
            b0 = *(const uint4*)(gB0 + kn);
            b1 = *(const uint4*)(gB0 + kn + 8);
        }
#pragma unroll
        for (int ks = 0; ks < 2; ++ks) {
            short8 af[2], bfr[2];
#pragma unroll
            for (int mi = 0; mi < 2; ++mi)
                af[mi] = *(const short8*)(ldsA + (wm * 32 + mi * 16 + lr) * LDK + ks * 32 + q * 8);
#pragma unroll
            for (int ni = 0; ni < 2; ++ni)
                bfr[ni] = *(const short8*)(ldsB + (wn * 32 + ni * 16 + lr) * LDK + ks * 32 + q * 8);
#pragma unroll
            for (int mi = 0; mi < 2; ++mi)
#pragma unroll
                for (int ni = 0; ni < 2; ++ni)
                    acc[mi][ni] = __builtin_amdgcn_mfma_f32_16x16x32_bf16(af[mi], bfr[ni], acc[mi][ni], 0, 0, 0);
        }
    }

    __syncthreads();  // all waves done reading ldsA/ldsB; reuse smem for C tile

    if (MODE == 0) {
        // stage bf16 C tile [64][LDK] then coalesced 16B stores (2 per thread)
        unsigned short* C = (unsigned short*)smem;
#pragma unroll
        for (int mi = 0; mi < 2; ++mi) {
#pragma unroll
            for (int ni = 0; ni < 2; ++ni) {
                int cn = wn * 32 + ni * 16 + lr;
                float bv = bias[bn * 64 + cn];
                int rl0 = wm * 32 + mi * 16 + q * 4;
#pragma unroll
                for (int r4 = 0; r4 < 4; ++r4) {
                    float v = fmaxf(acc[mi][ni][r4] + bv, 0.0f);
                    C[(rl0 + r4) * LDK + cn] = f2bf(v);
                }
            }
        }
        __syncthreads();
#pragma unroll
        for (int j = 0; j < 2; ++j) {
            int chunk = t + j * 256;       // 512 chunks: 64 rows x 8 x 16B
            int row = chunk >> 3, h = chunk & 7;
            int rg = bm * 64 + row;
            if (rg < M) {
                short8 v = *(const short8*)(C + row * LDK + h * 8);
                if (deg[rg] <= 0) { short8 z = {0, 0, 0, 0, 0, 0, 0, 0}; v = z; }
                *(short8*)(outB + (long)rg * 1024 + bn * 64 + h * 8) = v;
            }
        }
    } else {
        // stage fp32 C tile [64][68] (17408 B) then coalesced float4 stores (4 per thread)
        float* Cf = (float*)smem;
#pragma unroll
        for (int mi = 0; mi < 2; ++mi) {
#pragma unroll
            for (int ni = 0; ni < 2; ++ni) {
                int cn = wn * 32 + ni * 16 + lr;
                float bv = bias[bn * 64 + cn];
                int rl0 = wm * 32 + mi * 16 + q * 4;
#pragma unroll
                for (int r4 = 0; r4 < 4; ++r4)
                    Cf[(rl0 + r4) * 68 + cn] = acc[mi][ni][r4] + bv;
            }
        }
        __syncthreads();
#pragma unroll
        for (int j = 0; j < 4; ++j) {
            int chunk = t + j * 256;       // 1024 chunks: 64 rows x 16 x 16B
            int row = chunk >> 4, h = chunk & 15;
            int rg = bm * 64 + row;
            if (rg < M) {
                float4 v = *(const float4*)(Cf + row * 68 + h * 4);
                *(float4*)(outF + (long)rg * 256 + bn * 64 + h * 4) = v;
            }
        }
    }
}

extern "C" void kernel_launch(void* const* d_in, const int* in_sizes, int n_in,
                              void* d_out, int out_size, void* d_ws, size_t ws_size,
                              hipStream_t stream) {
    const float* x = (const float*)d_in[0];
    const int* ei = (const int*)d_in[1];
    const float* W[3] = {(const float*)d_in[2], (const float*)d_in[4], (const float*)d_in[6]};
    const float* b[3] = {(const float*)d_in[3], (const float*)d_in[5], (const float*)d_in[7]};
    const float* Wfp = (const float*)d_in[8];
    const float* bfp = (const float*)d_in[9];

    int N = in_sizes[0] / 256;
    int E = in_sizes[1] / 2;
    const int* src = ei;
    const int* dst = ei + E;

    char* p = (char*)d_ws;
    auto alloc = [&](size_t bytes) { char* r = p; p += (bytes + 255) & ~(size_t)255; return r; };
    int* deg = (int*)alloc((size_t)N * 4);
    int* offs = (int*)alloc((size_t)(N + 1) * 4);
    int* cursor = (int*)alloc((size_t)N * 4);
    int* esrc = (int*)alloc((size_t)E * 4);
    unsigned short* Wc[3];
    for (int l = 0; l < 3; l++) Wc[l] = (unsigned short*)alloc(256 * 512 * 2);
    unsigned short* Wft = (unsigned short*)alloc(256 * 1024 * 2);
    unsigned short* Ucat = (unsigned short*)alloc((size_t)N * 1024 * 2);
    unsigned short* Hbar = (unsigned short*)alloc((size_t)N * 256 * 2);

    hipMemsetAsync(deg, 0, (size_t)N * 4, stream);
    int EB = (E + 255) / 256;
    int xblocks = (N * 256 + 2047) / 2048;
    setup_kernel<<<EB + 448 + xblocks, 256, 0, stream>>>(dst, E, deg, W[0], W[1], W[2], Wfp, x,
                                                         Wc[0], Wc[1], Wc[2], Wft, Ucat, N, EB);
    int nb = (N + 127) / 128;   // 157
    scan_kernel<<<nb, 256, 0, stream>>>(deg, offs, cursor, N);
    fill_kernel<<<EB, 256, 0, stream>>>(src, dst, E, cursor, esrc);

    int gm = (N + 63) / 64;   // 313
    int ab = (N + 3) / 4;     // 5000
    for (int l = 0; l < 3; l++) {
        agg_kernel<<<ab, 256, 0, stream>>>(Ucat + l * 256, offs, esrc, Hbar, N);
        gemm_kernel<0, 512><<<dim3(gm, 4), 256, 0, stream>>>(Ucat + l * 256, Hbar, Wc[l], b[l],
                                                             deg, Ucat + (l + 1) * 256, nullptr, N);
    }
    gemm_kernel<1, 1024><<<dim3(gm, 4), 256, 0, stream>>>(Ucat, nullptr, Wft, bfp, nullptr,
                                                          nullptr, (float*)d_out, N);
}